// Round 12
// baseline (2703.129 us; speedup 1.0000x reference)
//
#include <hip/hip_runtime.h>
#include <stdint.h>

#define TN 1024
#define CD 192
#define NB 8
#define NCLUST 196
#define NMERGE (TN - NCLUST)          // 828 kept merges at the cut
#define PMX 128                        // max pairs merged per round / chunk rows

typedef unsigned long long ull;

// Workgroup barrier WITHOUT global-memory drain (LDS made visible only).
#define LBAR() asm volatile("s_waitcnt lgkmcnt(0)\n\ts_barrier" ::: "memory")
// Full fence barrier: drains global loads+stores too.
#define FBAR() asm volatile("s_waitcnt vmcnt(0) lgkmcnt(0)\n\ts_barrier" ::: "memory")

__device__ __forceinline__ uint32_t f2sort(float f) {
    uint32_t u = __float_as_uint(f);
    return u ^ ((u >> 31) ? 0xFFFFFFFFu : 0x80000000u);
}

template<int CTRL>
__device__ __forceinline__ ull dpp_min64(ull x) {
    int lo = (int)(uint32_t)x, hi = (int)(uint32_t)(x >> 32);
    int tlo = __builtin_amdgcn_update_dpp(lo, lo, CTRL, 0xF, 0xF, false);
    int thi = __builtin_amdgcn_update_dpp(hi, hi, CTRL, 0xF, 0xF, false);
    ull t = ((ull)(uint32_t)thi << 32) | (uint32_t)tlo;
    return (t < x) ? t : x;
}
__device__ __forceinline__ ull wmin64_all(ull x) {
    x = dpp_min64<0x111>(x); x = dpp_min64<0x112>(x);
    x = dpp_min64<0x114>(x); x = dpp_min64<0x118>(x);
    x = dpp_min64<0x142>(x); x = dpp_min64<0x143>(x);
    int lo = __builtin_amdgcn_readlane((int)(uint32_t)x, 63);
    int hi = __builtin_amdgcn_readlane((int)(uint32_t)(x >> 32), 63);
    return ((ull)(uint32_t)hi << 32) | (uint32_t)lo;
}

// ---------------- normalize rows: xn = x / ||x|| ----------------
__global__ void norm_kernel(const float* __restrict__ x, float* __restrict__ xn) {
    int row = blockIdx.x;
    int t = threadIdx.x;
    __shared__ float ssum[4];
    float v = 0.f;
    if (t < CD) v = x[(size_t)row * CD + t];
    float s = v * v;
    #pragma unroll
    for (int off = 32; off > 0; off >>= 1) s += __shfl_xor(s, off, 64);
    if ((t & 63) == 0) ssum[t >> 6] = s;
    __syncthreads();
    float tot = ssum[0] + ssum[1] + ssum[2] + ssum[3];
    float nrm = __fsqrt_rn(tot);
    if (t < CD) xn[(size_t)row * CD + t] = __fdiv_rn(v, nrm);
}

// ---------------- dist = 1 - xn @ xn^T, 64x64 tiles ----------------
#define KC 32
__global__ __launch_bounds__(256) void dist_kernel(const float* __restrict__ xn,
                                                   float* __restrict__ dout,
                                                   float* __restrict__ dwork) {
    int b = blockIdx.z;
    int bm = blockIdx.y, bn = blockIdx.x;
    const float* X = xn + (size_t)b * TN * CD;
    __shared__ float As[KC][68];
    __shared__ float Bs[KC][68];
    int tid = threadIdx.x;
    int tx = tid & 15, ty = tid >> 4;
    int lr = tid >> 2;
    int lq = tid & 3;
    float acc[4][4];
    #pragma unroll
    for (int r = 0; r < 4; ++r)
        #pragma unroll
        for (int c = 0; c < 4; ++c) acc[r][c] = 0.f;

    for (int kc = 0; kc < CD; kc += KC) {
        float4 a0 = *(const float4*)&X[(size_t)(bm * 64 + lr) * CD + kc + lq * 4];
        float4 a1 = *(const float4*)&X[(size_t)(bm * 64 + lr) * CD + kc + (lq + 4) * 4];
        float4 b0 = *(const float4*)&X[(size_t)(bn * 64 + lr) * CD + kc + lq * 4];
        float4 b1 = *(const float4*)&X[(size_t)(bn * 64 + lr) * CD + kc + (lq + 4) * 4];
        __syncthreads();
        As[lq * 4 + 0][lr] = a0.x; As[lq * 4 + 1][lr] = a0.y;
        As[lq * 4 + 2][lr] = a0.z; As[lq * 4 + 3][lr] = a0.w;
        As[lq * 4 + 16][lr] = a1.x; As[lq * 4 + 17][lr] = a1.y;
        As[lq * 4 + 18][lr] = a1.z; As[lq * 4 + 19][lr] = a1.w;
        Bs[lq * 4 + 0][lr] = b0.x; Bs[lq * 4 + 1][lr] = b0.y;
        Bs[lq * 4 + 2][lr] = b0.z; Bs[lq * 4 + 3][lr] = b0.w;
        Bs[lq * 4 + 16][lr] = b1.x; Bs[lq * 4 + 17][lr] = b1.y;
        Bs[lq * 4 + 18][lr] = b1.z; Bs[lq * 4 + 19][lr] = b1.w;
        __syncthreads();
        #pragma unroll
        for (int kk = 0; kk < KC; ++kk) {
            float4 av = *(const float4*)&As[kk][ty * 4];
            float4 bv = *(const float4*)&Bs[kk][tx * 4];
            acc[0][0] += av.x * bv.x; acc[0][1] += av.x * bv.y;
            acc[0][2] += av.x * bv.z; acc[0][3] += av.x * bv.w;
            acc[1][0] += av.y * bv.x; acc[1][1] += av.y * bv.y;
            acc[1][2] += av.y * bv.z; acc[1][3] += av.y * bv.w;
            acc[2][0] += av.z * bv.x; acc[2][1] += av.z * bv.y;
            acc[2][2] += av.z * bv.z; acc[2][3] += av.z * bv.w;
            acc[3][0] += av.w * bv.x; acc[3][1] += av.w * bv.y;
            acc[3][2] += av.w * bv.z; acc[3][3] += av.w * bv.w;
        }
    }
    size_t obase = (size_t)b * TN * TN;
    #pragma unroll
    for (int r = 0; r < 4; ++r) {
        int mrow = bm * 64 + ty * 4 + r;
        float4 o;
        o.x = 1.0f - acc[r][0]; o.y = 1.0f - acc[r][1];
        o.z = 1.0f - acc[r][2]; o.w = 1.0f - acc[r][3];
        size_t idx = obase + (size_t)mrow * TN + bn * 64 + tx * 4;
        *(float4*)&dout[idx] = o;
        *(float4*)&dwork[idx] = o;
    }
}

// ---------------- parallel mutual-NN agglomeration with per-round compaction ----------------
// Per round (current count N, matrix stride N, everything alive):
//  P1 NN scan -> P2 mutual pairs (select P smallest by (val,gid_i,gid_j)) -> P3 LW rows T +
//  two-level cross fixes F -> compact matrix to N-P in place (ascending 128-row chunks via
//  2 bounce buffers; writes of new rows < c never touch old rows >= c). gid = original
//  representative (min member). Epilogue: cut 828 smallest-height merges, union-find, rank.
__global__ __launch_bounds__(1024) void cluster_kernel(float* __restrict__ D,
                                                       float* __restrict__ Tg,
                                                       float* __restrict__ C0g,
                                                       float* __restrict__ C1g,
                                                       float* __restrict__ Fg,
                                                       float* __restrict__ out_labels) {
    int b = blockIdx.x;
    float* Db = D + (size_t)b * TN * TN;
    float* Tb = Tg + (size_t)b * PMX * TN;
    float* Cb0 = C0g + (size_t)b * PMX * TN;
    float* Cb1 = C1g + (size_t)b * PMX * TN;
    float* Fb = Fg + (size_t)b * PMX * PMX;
    int k = threadIdx.x;
    int lane = k & 63, wave = k >> 6;

    __shared__ ull rowkey[TN];            // (f2sort(val)<<32)|col (current index space)
    __shared__ float sizes_l[TN];
    __shared__ int gid_l[TN];             // original representative (min member)
    __shared__ int tslot_l[TN];           // pair slot if merged target this round, else -1
    __shared__ int new2old[TN];           // compaction map (per round); reused as parent in epilogue
    __shared__ uint32_t deadw[32];        // per-round dead mask; reused as root mask in epilogue
    __shared__ int pi_l[512], pj_l[512];
    __shared__ ull pkey_l[512];
    __shared__ int spi[PMX], spj[PMX];
    __shared__ ull skey[PMX];
    __shared__ ull mkey[TN];              // merge records: (vbits<<20)|(gid_i<<10)|gid_j
    __shared__ int npair;
    __shared__ int woff[32];

    sizes_l[k] = 1.0f;
    gid_l[k] = k;
    tslot_l[k] = -1;
    mkey[k] = ~0ull;
    __syncthreads();

    int N = TN;
    int nmerged = 0;

    while (nmerged < TN - 1) {
        // ---- P1: NN for every row (wave per row, matrix fully fresh) ----
        for (int r = wave; r < N; r += 16) {
            const float* Rr = Db + (size_t)r * N;
            ull best = ~0ull;
            for (int s = lane; s < N; s += 64) {
                if (s != r) {
                    ull key = ((ull)f2sort(Rr[s]) << 32) | (uint32_t)s;
                    if (key < best) best = key;
                }
            }
            best = wmin64_all(best);
            if (lane == 0) rowkey[r] = best;
        }
        if (k == 0) npair = 0;
        if (k < 32) deadw[k] = 0;
        LBAR();

        // ---- P2: mutual-NN pairs; key = (val, gid_i, gid_j) ----
        if (k < N) {
            ull K = rowkey[k];
            int c = (int)(uint32_t)K;
            if ((int)(uint32_t)rowkey[c] == k && k < c) {
                int idx = atomicAdd(&npair, 1);
                uint32_t vb = (uint32_t)(K >> 32);
                pi_l[idx] = k; pj_l[idx] = c;
                pkey_l[idx] = ((ull)vb << 20) | ((uint32_t)gid_l[k] << 10) | (uint32_t)gid_l[c];
            }
        }
        LBAR();
        int np = npair;
        if (np == 0) break;                     // unreachable (global-min pair is mutual); safety
        int P = np < PMX ? np : PMX;
        if (k < np) {                           // select P smallest keys (distinct), sorted
            ull mykey = pkey_l[k];
            int rank = 0;
            for (int u = 0; u < np; ++u) if (pkey_l[u] < mykey) ++rank;
            if (rank < P) { spi[rank] = pi_l[k]; spj[rank] = pj_l[k]; skey[rank] = mykey; }
        }
        LBAR();
        if (k < P) mkey[nmerged + k] = skey[k];

        // ---- P3: LW merged rows -> T (from pre-merge D); two-level cross fixes -> F ----
        for (int q = wave; q < P; q += 16) {
            int i = spi[q], j = spj[q];
            float ni = sizes_l[i], nj = sizes_l[j];
            float ss = __fadd_rn(ni, nj);
            const float* Ri = Db + (size_t)i * N;
            const float* Rj = Db + (size_t)j * N;
            float* Tq = Tb + (size_t)q * TN;
            for (int s = lane; s < N; s += 64)
                Tq[s] = __fdiv_rn(__fadd_rn(__fmul_rn(ni, Ri[s]), __fmul_rn(nj, Rj[s])), ss);
        }
        for (int t = k; t < P * P; t += 1024) {
            int p = t / P, q = t - p * P;
            if (p < q) {                        // p merges first (smaller key): LW_q(LW_p(old))
                int ip = spi[p], jp = spj[p], iq = spi[q], jq = spj[q];
                float nip = sizes_l[ip], njp = sizes_l[jp], sp = __fadd_rn(nip, njp);
                float niq = sizes_l[iq], njq = sizes_l[jq], sq = __fadd_rn(niq, njq);
                float t1 = __fdiv_rn(__fadd_rn(__fmul_rn(nip, Db[(size_t)ip * N + iq]),
                                               __fmul_rn(njp, Db[(size_t)jp * N + iq])), sp);
                float t2 = __fdiv_rn(__fadd_rn(__fmul_rn(nip, Db[(size_t)ip * N + jq]),
                                               __fmul_rn(njp, Db[(size_t)jp * N + jq])), sp);
                Fb[p * PMX + q] = __fdiv_rn(__fadd_rn(__fmul_rn(niq, t1), __fmul_rn(njq, t2)), sq);
            }
        }
        LBAR();                                  // all sizes reads done before updates

        // ---- bookkeeping: dead mask, target slots, merged sizes ----
        if (k < P) {
            int i = spi[k], j = spj[k];
            tslot_l[i] = k;
            atomicOr(&deadw[j >> 5], 1u << (j & 31));
            sizes_l[i] = __fadd_rn(sizes_l[i], sizes_l[j]);
        }
        LBAR();
        // new2old: stable compaction of survivors
        int nidx = -1;
        if (k < N) {
            uint32_t w = k >> 5, bp = k & 31;
            int db = 0;
            for (uint32_t u = 0; u < w; ++u) db += __popc(deadw[u]);
            db += __popc(deadw[w] & ((1u << bp) - 1u));
            if (!((deadw[w] >> bp) & 1u)) { nidx = k - db; new2old[nidx] = k; }
        }
        FBAR();                                  // T,F landed; all pre-merge D reads drained

        // ---- compaction: ascending chunks of PMX new rows, 2 bounce buffers ----
        int Nn = N - P;
        int nch = (Nn + PMX - 1) / PMX;
        for (int c = 0; c <= nch; ++c) {
            if (c > 0) {                         // W(c-1): bounce -> new layout (coalesced)
                int c0 = (c - 1) * PMX, c1 = c0 + PMX < Nn ? c0 + PMX : Nn;
                const float* Cc = ((c - 1) & 1) ? Cb1 : Cb0;
                for (int a = c0 + wave; a < c1; a += 16) {
                    const float* src = Cc + (size_t)(a - c0) * TN;
                    float* dst = Db + (size_t)a * Nn;
                    for (int s = lane; s < Nn; s += 64) dst[s] = src[s];
                }
            }
            if (c < nch) {                       // R(c): gather fresh values -> bounce
                int c0 = c * PMX, c1 = c0 + PMX < Nn ? c0 + PMX : Nn;
                float* Cc = (c & 1) ? Cb1 : Cb0;
                for (int ap = c0 + wave; ap < c1; ap += 16) {
                    int a = new2old[ap];
                    int qa = tslot_l[a];
                    float* dstC = Cc + (size_t)(ap - c0) * TN;
                    const float* RowA = Db + (size_t)a * N;
                    const float* TqA = Tb + (size_t)(qa >= 0 ? qa : 0) * TN;
                    for (int bp = lane; bp < Nn; bp += 64) {
                        int bo = new2old[bp];
                        int qb = tslot_l[bo];
                        float val;
                        if (qa >= 0) {
                            if (qb >= 0 && qb != qa) {
                                int p = qa < qb ? qa : qb, q = qa < qb ? qb : qa;
                                val = Fb[p * PMX + q];
                            } else val = TqA[bo];
                        } else if (qb >= 0) {
                            val = Tb[(size_t)qb * TN + a];
                        } else {
                            val = RowA[bo];
                        }
                        dstC[bp] = val;
                    }
                }
            }
            FBAR();
        }

        // ---- compact sizes/gid; reset tslot ----
        float tS = 0.f; int tG = 0;
        if (nidx >= 0) { tS = sizes_l[k]; tG = gid_l[k]; }
        LBAR();
        if (nidx >= 0) { sizes_l[nidx] = tS; gid_l[nidx] = tG; }
        tslot_l[k] = -1;
        N = Nn;
        nmerged += P;
        LBAR();
    }

    // ---- epilogue: cut at 828 smallest merge keys, union-find, rank labels ----
    __syncthreads();
    new2old[k] = k;                              // parent (original space)
    if (k < 32) deadw[k] = 0;                    // root mask
    __syncthreads();
    if (k < TN - 1) {
        ull mykey = mkey[k];
        if (mykey != ~0ull) {
            int rank = 0;
            for (int u = 0; u < TN - 1; ++u) if (mkey[u] < mykey) ++rank;
            if (rank < NMERGE) {
                int jj = (int)(mykey & 1023u);
                int ii = (int)((mykey >> 10) & 1023u);
                new2old[jj] = ii;                // parent[j] = i (i < j)
            }
        }
    }
    __syncthreads();
    #pragma unroll
    for (int it = 0; it < 11; ++it) {            // pointer jumping
        int p1 = new2old[k];
        int g = new2old[p1];
        __syncthreads();
        new2old[k] = g;
        __syncthreads();
    }
    if (new2old[k] == k) atomicOr(&deadw[k >> 5], 1u << (k & 31));
    __syncthreads();
    if (k == 0) {
        int run = 0;
        for (int w = 0; w < 32; ++w) { woff[w] = run; run += __popc(deadw[w]); }
    }
    __syncthreads();
    int p = new2old[k];
    int rank = woff[p >> 5] + __popc(deadw[p >> 5] & ((1u << (p & 31)) - 1u));
    out_labels[(size_t)b * TN + k] = (float)rank;
}

extern "C" void kernel_launch(void* const* d_in, const int* in_sizes, int n_in,
                              void* d_out, int out_size, void* d_ws, size_t ws_size,
                              hipStream_t stream) {
    const float* x = (const float*)d_in[0];
    float* out = (float*)d_out;

    float* xn    = (float*)d_ws;                          // NB*TN*CD floats (6.29 MB)
    float* Dwork = xn + (size_t)NB * TN * CD;             // NB*TN*TN floats (33.6 MB)
    float* Tg    = Dwork + (size_t)NB * TN * TN;          // NB*PMX*TN (4.19 MB)
    float* C0g   = Tg + (size_t)NB * PMX * TN;            // NB*PMX*TN (4.19 MB)
    float* C1g   = C0g + (size_t)NB * PMX * TN;           // NB*PMX*TN (4.19 MB)
    float* Fg    = C1g + (size_t)NB * PMX * TN;           // NB*PMX*PMX (0.52 MB)

    float* dist_out   = out;
    float* labels_out = out + (size_t)NB * TN * TN;

    norm_kernel<<<NB * TN, 256, 0, stream>>>(x, xn);
    dim3 g2(16, 16, NB);
    dist_kernel<<<g2, 256, 0, stream>>>(xn, dist_out, Dwork);
    cluster_kernel<<<NB, 1024, 0, stream>>>(Dwork, Tg, C0g, C1g, Fg, labels_out);
}

// Round 13
// 2150.340 us; speedup vs baseline: 1.2571x; 1.2571x over previous
//
#include <hip/hip_runtime.h>
#include <hip/hip_cooperative_groups.h>
#include <stdint.h>

namespace cg = cooperative_groups;

#define TN 1024
#define CD 192
#define NB 8
#define WPB 16                 // workgroups per batch
#define NWG (NB * WPB)
#define NCLUST 196
#define NMERGE (TN - NCLUST)

typedef unsigned long long ull;

__device__ __forceinline__ uint32_t f2sort(float f) {
    uint32_t u = __float_as_uint(f);
    return u ^ ((u >> 31) ? 0xFFFFFFFFu : 0x80000000u);
}

template<int CTRL>
__device__ __forceinline__ ull dpp_min64(ull x) {
    int lo = (int)(uint32_t)x, hi = (int)(uint32_t)(x >> 32);
    int tlo = __builtin_amdgcn_update_dpp(lo, lo, CTRL, 0xF, 0xF, false);
    int thi = __builtin_amdgcn_update_dpp(hi, hi, CTRL, 0xF, 0xF, false);
    ull t = ((ull)(uint32_t)thi << 32) | (uint32_t)tlo;
    return (t < x) ? t : x;
}
__device__ __forceinline__ ull wmin64_all(ull x) {
    x = dpp_min64<0x111>(x); x = dpp_min64<0x112>(x);
    x = dpp_min64<0x114>(x); x = dpp_min64<0x118>(x);
    x = dpp_min64<0x142>(x); x = dpp_min64<0x143>(x);
    int lo = __builtin_amdgcn_readlane((int)(uint32_t)x, 63);
    int hi = __builtin_amdgcn_readlane((int)(uint32_t)(x >> 32), 63);
    return ((ull)(uint32_t)hi << 32) | (uint32_t)lo;
}

// ---------------- normalize rows: xn = x / ||x|| ----------------
__global__ void norm_kernel(const float* __restrict__ x, float* __restrict__ xn) {
    int row = blockIdx.x;
    int t = threadIdx.x;
    __shared__ float ssum[4];
    float v = 0.f;
    if (t < CD) v = x[(size_t)row * CD + t];
    float s = v * v;
    #pragma unroll
    for (int off = 32; off > 0; off >>= 1) s += __shfl_xor(s, off, 64);
    if ((t & 63) == 0) ssum[t >> 6] = s;
    __syncthreads();
    float tot = ssum[0] + ssum[1] + ssum[2] + ssum[3];
    float nrm = __fsqrt_rn(tot);
    if (t < CD) xn[(size_t)row * CD + t] = __fdiv_rn(v, nrm);
}

// ---------------- dist = 1 - xn @ xn^T, 64x64 tiles ----------------
#define KC 32
__global__ __launch_bounds__(256) void dist_kernel(const float* __restrict__ xn,
                                                   float* __restrict__ dout) {
    int b = blockIdx.z;
    int bm = blockIdx.y, bn = blockIdx.x;
    const float* X = xn + (size_t)b * TN * CD;
    __shared__ float As[KC][68];
    __shared__ float Bs[KC][68];
    int tid = threadIdx.x;
    int tx = tid & 15, ty = tid >> 4;
    int lr = tid >> 2;
    int lq = tid & 3;
    float acc[4][4];
    #pragma unroll
    for (int r = 0; r < 4; ++r)
        #pragma unroll
        for (int c = 0; c < 4; ++c) acc[r][c] = 0.f;

    for (int kc = 0; kc < CD; kc += KC) {
        float4 a0 = *(const float4*)&X[(size_t)(bm * 64 + lr) * CD + kc + lq * 4];
        float4 a1 = *(const float4*)&X[(size_t)(bm * 64 + lr) * CD + kc + (lq + 4) * 4];
        float4 b0 = *(const float4*)&X[(size_t)(bn * 64 + lr) * CD + kc + lq * 4];
        float4 b1 = *(const float4*)&X[(size_t)(bn * 64 + lr) * CD + kc + (lq + 4) * 4];
        __syncthreads();
        As[lq * 4 + 0][lr] = a0.x; As[lq * 4 + 1][lr] = a0.y;
        As[lq * 4 + 2][lr] = a0.z; As[lq * 4 + 3][lr] = a0.w;
        As[lq * 4 + 16][lr] = a1.x; As[lq * 4 + 17][lr] = a1.y;
        As[lq * 4 + 18][lr] = a1.z; As[lq * 4 + 19][lr] = a1.w;
        Bs[lq * 4 + 0][lr] = b0.x; Bs[lq * 4 + 1][lr] = b0.y;
        Bs[lq * 4 + 2][lr] = b0.z; Bs[lq * 4 + 3][lr] = b0.w;
        Bs[lq * 4 + 16][lr] = b1.x; Bs[lq * 4 + 17][lr] = b1.y;
        Bs[lq * 4 + 18][lr] = b1.z; Bs[lq * 4 + 19][lr] = b1.w;
        __syncthreads();
        #pragma unroll
        for (int kk = 0; kk < KC; ++kk) {
            float4 av = *(const float4*)&As[kk][ty * 4];
            float4 bv = *(const float4*)&Bs[kk][tx * 4];
            acc[0][0] += av.x * bv.x; acc[0][1] += av.x * bv.y;
            acc[0][2] += av.x * bv.z; acc[0][3] += av.x * bv.w;
            acc[1][0] += av.y * bv.x; acc[1][1] += av.y * bv.y;
            acc[1][2] += av.y * bv.z; acc[1][3] += av.y * bv.w;
            acc[2][0] += av.z * bv.x; acc[2][1] += av.z * bv.y;
            acc[2][2] += av.z * bv.z; acc[2][3] += av.z * bv.w;
            acc[3][0] += av.w * bv.x; acc[3][1] += av.w * bv.y;
            acc[3][2] += av.w * bv.z; acc[3][3] += av.w * bv.w;
        }
    }
    size_t obase = (size_t)b * TN * TN;
    #pragma unroll
    for (int r = 0; r < 4; ++r) {
        int mrow = bm * 64 + ty * 4 + r;
        float4 o;
        o.x = 1.0f - acc[r][0]; o.y = 1.0f - acc[r][1];
        o.z = 1.0f - acc[r][2]; o.w = 1.0f - acc[r][3];
        size_t idx = obase + (size_t)mrow * TN + bn * 64 + tx * 4;
        *(float4*)&dout[idx] = o;
    }
}

// ---------------- cooperative parallel mutual-NN agglomeration ----------------
// 16 WGs per batch. Per round: plan (redundant per WG: mutual pairs from rowkeys,
// rank-sorted by (val,gid_i,gid_j); bookkeeping) -> rewrite D_cur(N) -> D_next(N-P)
// inline LW / two-level cross formulas (identical math to R12), NN key fused into the
// write pass -> 1 grid.sync. Rowkeys double-buffered in global. Epilogue (WG0/batch):
// cut 828 smallest merge keys, union-find, rank labels (identical to R12).
__global__ __launch_bounds__(1024)
void cluster_kernel(const float* __restrict__ Dinit,
                    float* __restrict__ DA, float* __restrict__ DB,
                    ull* __restrict__ rkg, int* __restrict__ done_g,
                    float* __restrict__ out_labels) {
    cg::grid_group grid = cg::this_grid();
    int wg = blockIdx.x;
    int b = wg >> 4;                 // WPB = 16
    int w = wg & 15;
    int k = threadIdx.x;
    int lane = k & 63, wv = k >> 6;
    int gw = w * 16 + wv;            // 0..255 batch-wide wave id

    __shared__ ull rk_s[TN];
    __shared__ float sz_s[TN];
    __shared__ int gid_s[TN];
    __shared__ int ts_s[TN];
    __shared__ int n2o_s[TN];
    __shared__ unsigned char dead_s[TN];
    __shared__ int pi_t[512], pj_t[512];
    __shared__ ull pk_t[512];
    __shared__ int spi_s[512], spj_s[512];
    __shared__ ull mk_s[TN];         // 1023 merge records
    __shared__ int wcnt[16], woffp[16];
    __shared__ int npair_s, allflag;
    __shared__ uint32_t rw[32];
    __shared__ int woff2[32];

    sz_s[k] = 1.0f;
    gid_s[k] = k;

    // ---- init: NN over Dinit -> rowkey parity 0 ----
    const float* D0 = Dinit + (size_t)b * TN * TN;
    for (int r = gw; r < TN; r += 256) {
        const float* Rr = D0 + (size_t)r * TN;
        ull best = ~0ull;
        for (int s = lane; s < TN; s += 64)
            if (s != r) {
                ull key = ((ull)f2sort(Rr[s]) << 32) | (uint32_t)s;
                if (key < best) best = key;
            }
        best = wmin64_all(best);
        if (lane == 0) rkg[(size_t)b * TN + r] = best;
    }
    __threadfence();
    grid.sync();

    float* DAb = DA + (size_t)b * TN * TN;
    float* DBb = DB + (size_t)b * TN * TN;
    const float* cur = D0;
    float* nxt = DAb;
    int par = 0;
    int N = TN, nmerged = 0;

    for (int round = 0; round < 1100; ++round) {
        bool work = (N > 1);
        int np = 0, Nn = N;
        if (work) {
            // ---- plan (redundant per WG, deterministic) ----
            if (k < N) rk_s[k] = rkg[(size_t)par * NB * TN + (size_t)b * TN + k];
            ts_s[k] = -1;
            dead_s[k] = 0;
            __syncthreads();
            bool mut = false; int cpart = 0;
            if (k < N) {
                ull K = rk_s[k];
                int c = (int)(uint32_t)K;
                if ((int)(uint32_t)rk_s[c] == k && k < c) { mut = true; cpart = c; }
            }
            ull bm = __ballot(mut);
            int lanepre = __popcll(bm & (((ull)1 << lane) - 1ull));
            if (lane == 0) wcnt[wv] = __popcll(bm);
            __syncthreads();
            if (k == 0) {
                int run = 0;
                #pragma unroll
                for (int u = 0; u < 16; ++u) { woffp[u] = run; run += wcnt[u]; }
                npair_s = run;
            }
            __syncthreads();
            if (mut) { int idx = woffp[wv] + lanepre; pi_t[idx] = k; pj_t[idx] = cpart; }
            __syncthreads();
            np = npair_s;
            if (np == 0) {                       // defensive: force global-min pair
                ull cand = ~0ull;
                if (k < N) cand = (rk_s[k] & 0xFFFFFFFF00000000ull) | (uint32_t)k;
                ull wmn = wmin64_all(cand);
                if (lane == 0) pk_t[wv] = wmn;
                __syncthreads();
                if (k == 0) {
                    ull g = pk_t[0];
                    for (int u = 1; u < 16; ++u) if (pk_t[u] < g) g = pk_t[u];
                    int r = (int)(uint32_t)g;
                    int c = (int)(uint32_t)rk_s[r];
                    pi_t[0] = r < c ? r : c;
                    pj_t[0] = r < c ? c : r;
                    npair_s = 1;
                }
                __syncthreads();
                np = 1;
            }
            if (k < np) {
                int i = pi_t[k], j = pj_t[k];
                uint32_t vb = (uint32_t)(rk_s[i] >> 32);
                pk_t[k] = ((ull)vb << 20) | ((ull)(uint32_t)gid_s[i] << 10) | (ull)(uint32_t)gid_s[j];
            }
            __syncthreads();
            if (k < np) {                        // rank-sort (keys distinct: gid_j unique)
                ull mk = pk_t[k];
                int rank = 0;
                for (int u = 0; u < np; ++u) if (pk_t[u] < mk) ++rank;
                spi_s[rank] = pi_t[k]; spj_s[rank] = pj_t[k];
                mk_s[nmerged + rank] = mk;
            }
            __syncthreads();
            if (k < np) { ts_s[spi_s[k]] = k; dead_s[spj_s[k]] = 1; }
            __syncthreads();
            bool alive = (k < N) && !dead_s[k];
            ull am = __ballot(alive);
            int apre = __popcll(am & (((ull)1 << lane) - 1ull));
            if (lane == 0) wcnt[wv] = __popcll(am);
            __syncthreads();
            if (k == 0) {
                int run = 0;
                #pragma unroll
                for (int u = 0; u < 16; ++u) { woffp[u] = run; run += wcnt[u]; }
            }
            __syncthreads();
            if (alive) n2o_s[woffp[wv] + apre] = k;
            Nn = N - np;
            if (w == 0 && k == 0) done_g[b] = Nn;
            __syncthreads();

            // ---- rewrite cur(N) -> nxt(Nn) + fused NN -> rowkey parity^1 ----
            for (int ap = gw; ap < Nn; ap += 256) {
                int a = n2o_s[ap];
                int qa = ts_s[a];
                float* drow = nxt + (size_t)ap * Nn;
                ull best = ~0ull;
                if (qa < 0) {
                    const float* Ra = cur + (size_t)a * N;
                    for (int bp = lane; bp < Nn; bp += 64) {
                        int bo = n2o_s[bp];
                        int qb = ts_s[bo];
                        float val;
                        if (qb < 0) val = Ra[bo];
                        else {
                            int iq = spi_s[qb], jq = spj_s[qb];
                            float niq = sz_s[iq], njq = sz_s[jq];
                            float sq = __fadd_rn(niq, njq);
                            val = __fdiv_rn(__fadd_rn(__fmul_rn(niq, Ra[iq]),
                                                      __fmul_rn(njq, Ra[jq])), sq);
                        }
                        drow[bp] = val;
                        if (bp != ap) {
                            ull key = ((ull)f2sort(val) << 32) | (uint32_t)bp;
                            if (key < best) best = key;
                        }
                    }
                } else {
                    int ii = spi_s[qa], jj = spj_s[qa];
                    float ni = sz_s[ii], nj = sz_s[jj], ss = __fadd_rn(ni, nj);
                    const float* Ri = cur + (size_t)ii * N;
                    const float* Rj = cur + (size_t)jj * N;
                    for (int bp = lane; bp < Nn; bp += 64) {
                        int bo = n2o_s[bp];
                        int qb = ts_s[bo];
                        float val;
                        if (qb < 0) {
                            val = __fdiv_rn(__fadd_rn(__fmul_rn(ni, Ri[bo]),
                                                      __fmul_rn(nj, Rj[bo])), ss);
                        } else if (qb == qa) {
                            val = 0.0f;          // diagonal, never read
                        } else {
                            int p = qa < qb ? qa : qb, q2 = qa < qb ? qb : qa;
                            int ip = spi_s[p], jp = spj_s[p], iq = spi_s[q2], jq = spj_s[q2];
                            float nip = sz_s[ip], njp = sz_s[jp], sp = __fadd_rn(nip, njp);
                            float niq = sz_s[iq], njq = sz_s[jq], sq = __fadd_rn(niq, njq);
                            float t1 = __fdiv_rn(__fadd_rn(__fmul_rn(nip, cur[(size_t)ip * N + iq]),
                                                           __fmul_rn(njp, cur[(size_t)jp * N + iq])), sp);
                            float t2 = __fdiv_rn(__fadd_rn(__fmul_rn(nip, cur[(size_t)ip * N + jq]),
                                                           __fmul_rn(njp, cur[(size_t)jp * N + jq])), sp);
                            val = __fdiv_rn(__fadd_rn(__fmul_rn(niq, t1), __fmul_rn(njq, t2)), sq);
                        }
                        drow[bp] = val;
                        if (bp != ap) {
                            ull key = ((ull)f2sort(val) << 32) | (uint32_t)bp;
                            if (key < best) best = key;
                        }
                    }
                }
                best = wmin64_all(best);
                if (lane == 0) rkg[(size_t)(par ^ 1) * NB * TN + (size_t)b * TN + ap] = best;
            }
            __syncthreads();
            // compact sizes/gid (WG-local)
            float ns = 0.f; int ng = 0; bool act = (k < Nn);
            if (act) {
                int a = n2o_s[k]; int q = ts_s[a];
                ns = (q >= 0) ? __fadd_rn(sz_s[spi_s[q]], sz_s[spj_s[q]]) : sz_s[a];
                ng = gid_s[a];
            }
            __syncthreads();
            if (act) { sz_s[k] = ns; gid_s[k] = ng; }
            nmerged += np;
            N = Nn;
        } else {
            if (w == 0 && k == 0) done_g[b] = 1;
        }
        __threadfence();
        grid.sync();
        if (k == 0) {
            int all = 1;
            #pragma unroll
            for (int u = 0; u < NB; ++u) all &= (done_g[u] == 1);
            allflag = all;
        }
        __syncthreads();
        if (work) {                   // advance ping-pong only if we rewrote
            cur = nxt;
            nxt = (nxt == DAb) ? DBb : DAb;
            par ^= 1;
        }
        if (allflag) break;
    }

    // ---- epilogue (WG 0 of each batch): cut + union-find + rank labels ----
    if (w == 0) {
        __syncthreads();
        n2o_s[k] = k;
        if (k < 32) rw[k] = 0;
        __syncthreads();
        if (k < TN - 1) {
            ull mk = mk_s[k];
            int rank = 0;
            for (int u = 0; u < TN - 1; ++u) if (mk_s[u] < mk) ++rank;
            if (rank < NMERGE) {
                int jj = (int)(mk & 1023ull);
                int ii = (int)((mk >> 10) & 1023ull);
                n2o_s[jj] = ii;        // parent in ORIGINAL index space (ii < jj)
            }
        }
        __syncthreads();
        #pragma unroll
        for (int it = 0; it < 11; ++it) {
            int p1 = n2o_s[k];
            int g = n2o_s[p1];
            __syncthreads();
            n2o_s[k] = g;
            __syncthreads();
        }
        if (n2o_s[k] == k) atomicOr(&rw[k >> 5], 1u << (k & 31));
        __syncthreads();
        if (k == 0) {
            int run = 0;
            for (int u = 0; u < 32; ++u) { woff2[u] = run; run += __popc(rw[u]); }
        }
        __syncthreads();
        int p = n2o_s[k];
        int rank = woff2[p >> 5] + __popc(rw[p >> 5] & ((1u << (p & 31)) - 1u));
        out_labels[(size_t)b * TN + k] = (float)rank;
    }
}

extern "C" void kernel_launch(void* const* d_in, const int* in_sizes, int n_in,
                              void* d_out, int out_size, void* d_ws, size_t ws_size,
                              hipStream_t stream) {
    const float* x = (const float*)d_in[0];
    float* out = (float*)d_out;

    float* xn  = (float*)d_ws;                              // NB*TN*CD  (6.29 MB)
    float* DAp = xn + (size_t)NB * TN * CD;                 // NB*TN*TN  (33.6 MB)
    float* DBp = DAp + (size_t)NB * TN * TN;                // NB*TN*TN  (33.6 MB)
    ull*   rkg = (ull*)(DBp + (size_t)NB * TN * TN);        // 2*NB*TN u64 (128 KB)
    int*   doneg = (int*)(rkg + 2 * (size_t)NB * TN);       // NB ints

    float* dist_out   = out;
    float* labels_out = out + (size_t)NB * TN * TN;

    norm_kernel<<<NB * TN, 256, 0, stream>>>(x, xn);
    dim3 g2(16, 16, NB);
    dist_kernel<<<g2, 256, 0, stream>>>(xn, dist_out);

    const float* Dinit = dist_out;                          // round-0 input (read-only)
    void* args[] = { (void*)&Dinit, (void*)&DAp, (void*)&DBp,
                     (void*)&rkg, (void*)&doneg, (void*)&labels_out };
    hipLaunchCooperativeKernel((const void*)cluster_kernel, dim3(NWG), dim3(1024),
                               args, 0, stream);
}

// Round 14
// 1146.410 us; speedup vs baseline: 2.3579x; 1.8757x over previous
//
#include <hip/hip_runtime.h>
#include <hip/hip_cooperative_groups.h>
#include <stdint.h>

namespace cg = cooperative_groups;

#define TN 1024
#define CD 192
#define NB 8
#define WPB 16
#define NWG (NB * WPB)
#define NCLUST 196
#define NMERGE (TN - NCLUST)
#define TAILN 168              // handoff threshold (168^2 floats fit in LDS)
#define PCAP 64                // tail: max pairs per round
#define HIMASK 0xFFFFFFFF00000000ull

typedef unsigned long long ull;

__device__ __forceinline__ uint32_t f2sort(float f) {
    uint32_t u = __float_as_uint(f);
    return u ^ ((u >> 31) ? 0xFFFFFFFFu : 0x80000000u);
}

template<int CTRL>
__device__ __forceinline__ ull dpp_min64(ull x) {
    int lo = (int)(uint32_t)x, hi = (int)(uint32_t)(x >> 32);
    int tlo = __builtin_amdgcn_update_dpp(lo, lo, CTRL, 0xF, 0xF, false);
    int thi = __builtin_amdgcn_update_dpp(hi, hi, CTRL, 0xF, 0xF, false);
    ull t = ((ull)(uint32_t)thi << 32) | (uint32_t)tlo;
    return (t < x) ? t : x;
}
__device__ __forceinline__ ull wmin64_all(ull x) {
    x = dpp_min64<0x111>(x); x = dpp_min64<0x112>(x);
    x = dpp_min64<0x114>(x); x = dpp_min64<0x118>(x);
    x = dpp_min64<0x142>(x); x = dpp_min64<0x143>(x);
    int lo = __builtin_amdgcn_readlane((int)(uint32_t)x, 63);
    int hi = __builtin_amdgcn_readlane((int)(uint32_t)(x >> 32), 63);
    return ((ull)(uint32_t)hi << 32) | (uint32_t)lo;
}

// ---------------- normalize rows: xn = x / ||x|| ----------------
__global__ void norm_kernel(const float* __restrict__ x, float* __restrict__ xn) {
    int row = blockIdx.x;
    int t = threadIdx.x;
    __shared__ float ssum[4];
    float v = 0.f;
    if (t < CD) v = x[(size_t)row * CD + t];
    float s = v * v;
    #pragma unroll
    for (int off = 32; off > 0; off >>= 1) s += __shfl_xor(s, off, 64);
    if ((t & 63) == 0) ssum[t >> 6] = s;
    __syncthreads();
    float tot = ssum[0] + ssum[1] + ssum[2] + ssum[3];
    float nrm = __fsqrt_rn(tot);
    if (t < CD) xn[(size_t)row * CD + t] = __fdiv_rn(v, nrm);
}

// ---------------- dist = 1 - xn @ xn^T, 64x64 tiles ----------------
#define KC 32
__global__ __launch_bounds__(256) void dist_kernel(const float* __restrict__ xn,
                                                   float* __restrict__ dout) {
    int b = blockIdx.z;
    int bm = blockIdx.y, bn = blockIdx.x;
    const float* X = xn + (size_t)b * TN * CD;
    __shared__ float As[KC][68];
    __shared__ float Bs[KC][68];
    int tid = threadIdx.x;
    int tx = tid & 15, ty = tid >> 4;
    int lr = tid >> 2;
    int lq = tid & 3;
    float acc[4][4];
    #pragma unroll
    for (int r = 0; r < 4; ++r)
        #pragma unroll
        for (int c = 0; c < 4; ++c) acc[r][c] = 0.f;

    for (int kc = 0; kc < CD; kc += KC) {
        float4 a0 = *(const float4*)&X[(size_t)(bm * 64 + lr) * CD + kc + lq * 4];
        float4 a1 = *(const float4*)&X[(size_t)(bm * 64 + lr) * CD + kc + (lq + 4) * 4];
        float4 b0 = *(const float4*)&X[(size_t)(bn * 64 + lr) * CD + kc + lq * 4];
        float4 b1 = *(const float4*)&X[(size_t)(bn * 64 + lr) * CD + kc + (lq + 4) * 4];
        __syncthreads();
        As[lq * 4 + 0][lr] = a0.x; As[lq * 4 + 1][lr] = a0.y;
        As[lq * 4 + 2][lr] = a0.z; As[lq * 4 + 3][lr] = a0.w;
        As[lq * 4 + 16][lr] = a1.x; As[lq * 4 + 17][lr] = a1.y;
        As[lq * 4 + 18][lr] = a1.z; As[lq * 4 + 19][lr] = a1.w;
        Bs[lq * 4 + 0][lr] = b0.x; Bs[lq * 4 + 1][lr] = b0.y;
        Bs[lq * 4 + 2][lr] = b0.z; Bs[lq * 4 + 3][lr] = b0.w;
        Bs[lq * 4 + 16][lr] = b1.x; Bs[lq * 4 + 17][lr] = b1.y;
        Bs[lq * 4 + 18][lr] = b1.z; Bs[lq * 4 + 19][lr] = b1.w;
        __syncthreads();
        #pragma unroll
        for (int kk = 0; kk < KC; ++kk) {
            float4 av = *(const float4*)&As[kk][ty * 4];
            float4 bv = *(const float4*)&Bs[kk][tx * 4];
            acc[0][0] += av.x * bv.x; acc[0][1] += av.x * bv.y;
            acc[0][2] += av.x * bv.z; acc[0][3] += av.x * bv.w;
            acc[1][0] += av.y * bv.x; acc[1][1] += av.y * bv.y;
            acc[1][2] += av.y * bv.z; acc[1][3] += av.y * bv.w;
            acc[2][0] += av.z * bv.x; acc[2][1] += av.z * bv.y;
            acc[2][2] += av.z * bv.z; acc[2][3] += av.z * bv.w;
            acc[3][0] += av.w * bv.x; acc[3][1] += av.w * bv.y;
            acc[3][2] += av.w * bv.z; acc[3][3] += av.w * bv.w;
        }
    }
    size_t obase = (size_t)b * TN * TN;
    #pragma unroll
    for (int r = 0; r < 4; ++r) {
        int mrow = bm * 64 + ty * 4 + r;
        float4 o;
        o.x = 1.0f - acc[r][0]; o.y = 1.0f - acc[r][1];
        o.z = 1.0f - acc[r][2]; o.w = 1.0f - acc[r][3];
        size_t idx = obase + (size_t)mrow * TN + bn * 64 + tx * 4;
        *(float4*)&dout[idx] = o;
    }
}

// ---------------- Kernel A: cooperative head (rounds while N > TAILN) ----------------
__global__ __launch_bounds__(1024)
void cluster_kernel(const float* __restrict__ Dinit,
                    float* __restrict__ DA, float* __restrict__ DB,
                    ull* __restrict__ rkg, int* __restrict__ done_g,
                    float* __restrict__ szg, int* __restrict__ gidg,
                    ull* __restrict__ mkg, int* __restrict__ metag) {
    cg::grid_group grid = cg::this_grid();
    int wg = blockIdx.x;
    int b = wg % NB;
    int w = wg / NB;
    int k = threadIdx.x;
    int lane = k & 63, wv = k >> 6;
    int gw = w * 16 + wv;

    __shared__ ull rk_s[TN];
    __shared__ float sz_s[TN];
    __shared__ int gid_s[TN];
    __shared__ int ts_s[TN];
    __shared__ int n2o_s[TN];
    __shared__ unsigned char dead_s[TN];
    __shared__ int pi_t[512], pj_t[512];
    __shared__ ull pk_t[512];
    __shared__ int spi_s[512], spj_s[512];
    __shared__ ull mk_s[TN];
    __shared__ int wcnt[16], woffp[16];
    __shared__ int npair_s, allflag;

    sz_s[k] = 1.0f;
    gid_s[k] = k;
    mk_s[k] = ~0ull;

    // init: NN over Dinit -> rowkey parity 0
    const float* D0 = Dinit + (size_t)b * TN * TN;
    for (int r = gw; r < TN; r += 256) {
        const float* Rr = D0 + (size_t)r * TN;
        ull best = ~0ull;
        for (int s = lane; s < TN; s += 64)
            if (s != r) {
                ull key = ((ull)f2sort(Rr[s]) << 32) | (uint32_t)s;
                if (key < best) best = key;
            }
        best = wmin64_all(best);
        if (lane == 0) rkg[(size_t)b * TN + r] = best;
    }
    __threadfence();
    grid.sync();

    float* DAb = DA + (size_t)b * TN * TN;
    float* DBb = DB + (size_t)b * TN * TN;
    const float* cur = D0;
    float* nxt = DAb;
    int par = 0;
    int N = TN, nmerged = 0;

    for (int round = 0; round < 64; ++round) {
        bool work = (N > TAILN);
        int np = 0, Nn = N;
        if (work) {
            // plan (redundant per WG, deterministic)
            if (k < N) rk_s[k] = rkg[(size_t)par * NB * TN + (size_t)b * TN + k];
            ts_s[k] = -1;
            dead_s[k] = 0;
            __syncthreads();
            bool mut = false; int cpart = 0;
            if (k < N) {
                ull K = rk_s[k];
                int c = (int)(uint32_t)K;
                if ((int)(uint32_t)rk_s[c] == k && k < c) { mut = true; cpart = c; }
            }
            ull bm = __ballot(mut);
            int lanepre = __popcll(bm & (((ull)1 << lane) - 1ull));
            if (lane == 0) wcnt[wv] = __popcll(bm);
            __syncthreads();
            if (k == 0) {
                int run = 0;
                #pragma unroll
                for (int u = 0; u < 16; ++u) { woffp[u] = run; run += wcnt[u]; }
                npair_s = run;
            }
            __syncthreads();
            if (mut) { int idx = woffp[wv] + lanepre; pi_t[idx] = k; pj_t[idx] = cpart; }
            __syncthreads();
            np = npair_s;
            if (np == 0) {                       // defensive: force global-min pair
                ull cand = ~0ull;
                if (k < N) cand = (rk_s[k] & HIMASK) | (uint32_t)k;
                ull wmn = wmin64_all(cand);
                if (lane == 0) pk_t[wv] = wmn;
                __syncthreads();
                if (k == 0) {
                    ull g = pk_t[0];
                    for (int u = 1; u < 16; ++u) if (pk_t[u] < g) g = pk_t[u];
                    int r = (int)(uint32_t)g;
                    int c = (int)(uint32_t)rk_s[r];
                    pi_t[0] = r < c ? r : c;
                    pj_t[0] = r < c ? c : r;
                    npair_s = 1;
                }
                __syncthreads();
                np = 1;
            }
            if (k < np) {
                int i = pi_t[k], j = pj_t[k];
                uint32_t vb = (uint32_t)(rk_s[i] >> 32);
                pk_t[k] = ((ull)vb << 20) | ((ull)(uint32_t)gid_s[i] << 10) | (ull)(uint32_t)gid_s[j];
            }
            __syncthreads();
            if (k < np) {
                ull mk = pk_t[k];
                int rank = 0;
                for (int u = 0; u < np; ++u) if (pk_t[u] < mk) ++rank;
                spi_s[rank] = pi_t[k]; spj_s[rank] = pj_t[k];
                mk_s[nmerged + rank] = mk;
            }
            __syncthreads();
            if (k < np) { ts_s[spi_s[k]] = k; dead_s[spj_s[k]] = 1; }
            __syncthreads();
            bool alive = (k < N) && !dead_s[k];
            ull am = __ballot(alive);
            int apre = __popcll(am & (((ull)1 << lane) - 1ull));
            if (lane == 0) wcnt[wv] = __popcll(am);
            __syncthreads();
            if (k == 0) {
                int run = 0;
                #pragma unroll
                for (int u = 0; u < 16; ++u) { woffp[u] = run; run += wcnt[u]; }
            }
            __syncthreads();
            if (alive) n2o_s[woffp[wv] + apre] = k;
            Nn = N - np;
            if (w == 0 && k == 0) done_g[b] = (Nn <= TAILN) ? 1 : 0;
            __syncthreads();

            // rewrite cur(N) -> nxt(Nn) + fused NN
            for (int ap = gw; ap < Nn; ap += 256) {
                int a = n2o_s[ap];
                int qa = ts_s[a];
                float* drow = nxt + (size_t)ap * Nn;
                ull best = ~0ull;
                if (qa < 0) {
                    const float* Ra = cur + (size_t)a * N;
                    for (int bp = lane; bp < Nn; bp += 64) {
                        int bo = n2o_s[bp];
                        int qb = ts_s[bo];
                        float val;
                        if (qb < 0) val = Ra[bo];
                        else {
                            int iq = spi_s[qb], jq = spj_s[qb];
                            float niq = sz_s[iq], njq = sz_s[jq];
                            float sq = __fadd_rn(niq, njq);
                            val = __fdiv_rn(__fadd_rn(__fmul_rn(niq, Ra[iq]),
                                                      __fmul_rn(njq, Ra[jq])), sq);
                        }
                        drow[bp] = val;
                        if (bp != ap) {
                            ull key = ((ull)f2sort(val) << 32) | (uint32_t)bp;
                            if (key < best) best = key;
                        }
                    }
                } else {
                    int ii = spi_s[qa], jj = spj_s[qa];
                    float ni = sz_s[ii], nj = sz_s[jj], ss = __fadd_rn(ni, nj);
                    const float* Ri = cur + (size_t)ii * N;
                    const float* Rj = cur + (size_t)jj * N;
                    for (int bp = lane; bp < Nn; bp += 64) {
                        int bo = n2o_s[bp];
                        int qb = ts_s[bo];
                        float val;
                        if (qb < 0) {
                            val = __fdiv_rn(__fadd_rn(__fmul_rn(ni, Ri[bo]),
                                                      __fmul_rn(nj, Rj[bo])), ss);
                        } else if (qb == qa) {
                            val = 0.0f;
                        } else {
                            int p = qa < qb ? qa : qb, q2 = qa < qb ? qb : qa;
                            int ip = spi_s[p], jp = spj_s[p], iq = spi_s[q2], jq = spj_s[q2];
                            float nip = sz_s[ip], njp = sz_s[jp], sp = __fadd_rn(nip, njp);
                            float niq = sz_s[iq], njq = sz_s[jq], sq = __fadd_rn(niq, njq);
                            float t1 = __fdiv_rn(__fadd_rn(__fmul_rn(nip, cur[(size_t)ip * N + iq]),
                                                           __fmul_rn(njp, cur[(size_t)jp * N + iq])), sp);
                            float t2 = __fdiv_rn(__fadd_rn(__fmul_rn(nip, cur[(size_t)ip * N + jq]),
                                                           __fmul_rn(njp, cur[(size_t)jp * N + jq])), sp);
                            val = __fdiv_rn(__fadd_rn(__fmul_rn(niq, t1), __fmul_rn(njq, t2)), sq);
                        }
                        drow[bp] = val;
                        if (bp != ap) {
                            ull key = ((ull)f2sort(val) << 32) | (uint32_t)bp;
                            if (key < best) best = key;
                        }
                    }
                }
                best = wmin64_all(best);
                if (lane == 0) rkg[(size_t)(par ^ 1) * NB * TN + (size_t)b * TN + ap] = best;
            }
            __syncthreads();
            float ns = 0.f; int ng = 0; bool act = (k < Nn);
            if (act) {
                int a = n2o_s[k]; int q = ts_s[a];
                ns = (q >= 0) ? __fadd_rn(sz_s[spi_s[q]], sz_s[spj_s[q]]) : sz_s[a];
                ng = gid_s[a];
            }
            __syncthreads();
            if (act) { sz_s[k] = ns; gid_s[k] = ng; }
            nmerged += np;
            N = Nn;
        } else {
            if (w == 0 && k == 0) done_g[b] = 1;
        }
        __threadfence();
        grid.sync();
        if (k == 0) {
            int all = 1;
            #pragma unroll
            for (int u = 0; u < NB; ++u) all &= (done_g[u] == 1);
            allflag = all;
        }
        __syncthreads();
        if (work) {
            cur = nxt;
            nxt = (nxt == DAb) ? DBb : DAb;
            par ^= 1;
        }
        if (allflag) break;
    }

    // state dump for tail kernel (w==0 per batch)
    if (w == 0) {
        if (k < N) { szg[b * TN + k] = sz_s[k]; gidg[b * TN + k] = gid_s[k]; }
        mkg[(size_t)b * TN + k] = mk_s[k];
        if (k == 0) {
            metag[b * 4 + 0] = N;
            metag[b * 4 + 1] = nmerged;
            metag[b * 4 + 2] = (cur == DAb) ? 1 : 2;
        }
    }
}

// ---------------- Kernel B: LDS-resident tail + cut + labels ----------------
__global__ __launch_bounds__(1024)
void tail_kernel(const float* __restrict__ DA, const float* __restrict__ DB,
                 const float* __restrict__ szg, const int* __restrict__ gidg,
                 const ull* __restrict__ mkg, const int* __restrict__ metag,
                 float* __restrict__ out_labels) {
    int b = blockIdx.x;
    int k = threadIdx.x;
    int lane = k & 63, wv = k >> 6;

    __shared__ float Dl[TAILN * TAILN];
    __shared__ ull rk_s[TAILN];
    __shared__ float sz_s[TAILN];
    __shared__ int gid_s[TAILN];
    __shared__ unsigned char alive[TAILN];
    __shared__ int tsl[TAILN];
    __shared__ float F[PCAP * PCAP];
    __shared__ int pi_t[96], pj_t[96];
    __shared__ ull pk_t[96];
    __shared__ int spi_s[PCAP], spj_s[PCAP];
    __shared__ ull mk_s[TN];
    __shared__ int par_s[TN];
    __shared__ uint32_t rw[32];
    __shared__ int woff2[32];
    __shared__ ull wpA[16];
    __shared__ int npair_s;

    int N = metag[b * 4 + 0];
    int nm = metag[b * 4 + 1];
    int which = metag[b * 4 + 2];
    const float* src = ((which == 1) ? DA : DB) + (size_t)b * TN * TN;

    for (int idx = k; idx < N * N; idx += 1024) Dl[idx] = src[idx];
    mk_s[k] = mkg[(size_t)b * TN + k];
    if (k < N) {
        sz_s[k] = szg[b * TN + k];
        gid_s[k] = gidg[b * TN + k];
        alive[k] = 1;
        tsl[k] = -1;
    }
    __syncthreads();

    int na = N;
    for (int round = 0; round < 600 && na > 1; ++round) {
        // NN scan (LDS)
        for (int r = wv; r < N; r += 16) {
            ull best = ~0ull;
            if (alive[r]) {
                for (int s = lane; s < N; s += 64)
                    if (alive[s] && s != r) {
                        ull key = ((ull)f2sort(Dl[r * N + s]) << 32) | (uint32_t)s;
                        if (key < best) best = key;
                    }
                best = wmin64_all(best);
            }
            if (lane == 0) rk_s[r] = best;
        }
        if (k == 0) npair_s = 0;
        __syncthreads();
        // mutual pairs
        if (k < N && alive[k]) {
            ull K = rk_s[k];
            int c = (int)(uint32_t)K;
            if ((int)(uint32_t)rk_s[c] == k && k < c) {
                int idx = atomicAdd(&npair_s, 1);
                pi_t[idx] = k; pj_t[idx] = c;
            }
        }
        __syncthreads();
        int np = npair_s;
        if (np == 0) {
            ull cand = ~0ull;
            if (k < N && alive[k]) cand = (rk_s[k] & HIMASK) | (uint32_t)k;
            cand = wmin64_all(cand);
            if (lane == 0) wpA[wv] = cand;
            __syncthreads();
            if (k == 0) {
                ull g = wpA[0];
                for (int u = 1; u < 16; ++u) if (wpA[u] < g) g = wpA[u];
                int r = (int)(uint32_t)g;
                int c = (int)(uint32_t)rk_s[r];
                pi_t[0] = r < c ? r : c;
                pj_t[0] = r < c ? c : r;
                npair_s = 1;
            }
            __syncthreads();
            np = 1;
        }
        int P = np < PCAP ? np : PCAP;
        if (k < np) {
            int i = pi_t[k], j = pj_t[k];
            uint32_t vb = (uint32_t)(rk_s[i] >> 32);
            pk_t[k] = ((ull)vb << 20) | ((ull)(uint32_t)gid_s[i] << 10) | (ull)(uint32_t)gid_s[j];
        }
        __syncthreads();
        if (k < np) {
            ull mk = pk_t[k];
            int rank = 0;
            for (int u = 0; u < np; ++u) if (pk_t[u] < mk) ++rank;
            if (rank < P) { spi_s[rank] = pi_t[k]; spj_s[rank] = pj_t[k]; mk_s[nm + rank] = mk; }
        }
        __syncthreads();
        // F: two-level cross values from OLD Dl
        for (int t = k; t < P * P; t += 1024) {
            int p = t / P, q = t - p * P;
            if (p < q) {
                int ip = spi_s[p], jp = spj_s[p], iq = spi_s[q], jq = spj_s[q];
                float nip = sz_s[ip], njp = sz_s[jp], sp = __fadd_rn(nip, njp);
                float niq = sz_s[iq], njq = sz_s[jq], sq = __fadd_rn(niq, njq);
                float t1 = __fdiv_rn(__fadd_rn(__fmul_rn(nip, Dl[ip * N + iq]),
                                               __fmul_rn(njp, Dl[jp * N + iq])), sp);
                float t2 = __fdiv_rn(__fadd_rn(__fmul_rn(nip, Dl[ip * N + jq]),
                                               __fmul_rn(njp, Dl[jp * N + jq])), sp);
                F[p * PCAP + q] = __fdiv_rn(__fadd_rn(__fmul_rn(niq, t1), __fmul_rn(njq, t2)), sq);
            }
        }
        if (k < P) { tsl[spi_s[k]] = k; alive[spj_s[k]] = 0; }
        __syncthreads();
        // in-place row + column LW writes
        for (int q = wv; q < P; q += 16) {
            int ii = spi_s[q], jj = spj_s[q];
            float ni = sz_s[ii], nj = sz_s[jj], ss = __fadd_rn(ni, nj);
            for (int s = lane; s < N; s += 64) {
                if (!alive[s] || s == ii) continue;
                int tp = tsl[s];
                float val;
                if (tp >= 0) {
                    int p2 = tp < q ? tp : q, q2 = tp < q ? q : tp;
                    val = F[p2 * PCAP + q2];
                } else {
                    val = __fdiv_rn(__fadd_rn(__fmul_rn(ni, Dl[ii * N + s]),
                                              __fmul_rn(nj, Dl[jj * N + s])), ss);
                }
                Dl[ii * N + s] = val;
                Dl[s * N + ii] = val;
            }
        }
        __syncthreads();
        if (k < P) {
            int ii = spi_s[k];
            sz_s[ii] = __fadd_rn(sz_s[ii], sz_s[spj_s[k]]);
            tsl[ii] = -1;
        }
        nm += P;
        na -= P;
        __syncthreads();
    }

    // epilogue: cut at 828 smallest merge keys, union-find, rank labels
    __syncthreads();
    par_s[k] = k;
    if (k < 32) rw[k] = 0;
    __syncthreads();
    if (k < TN - 1) {
        ull mk = mk_s[k];
        if (mk != ~0ull) {
            int rank = 0;
            for (int u = 0; u < TN - 1; ++u) if (mk_s[u] < mk) ++rank;
            if (rank < NMERGE) {
                int jj = (int)(mk & 1023ull);
                int ii = (int)((mk >> 10) & 1023ull);
                par_s[jj] = ii;
            }
        }
    }
    __syncthreads();
    #pragma unroll
    for (int it = 0; it < 11; ++it) {
        int p1 = par_s[k];
        int g = par_s[p1];
        __syncthreads();
        par_s[k] = g;
        __syncthreads();
    }
    if (par_s[k] == k) atomicOr(&rw[k >> 5], 1u << (k & 31));
    __syncthreads();
    if (k == 0) {
        int run = 0;
        for (int u = 0; u < 32; ++u) { woff2[u] = run; run += __popc(rw[u]); }
    }
    __syncthreads();
    int p = par_s[k];
    int rank = woff2[p >> 5] + __popc(rw[p >> 5] & ((1u << (p & 31)) - 1u));
    out_labels[(size_t)b * TN + k] = (float)rank;
}

extern "C" void kernel_launch(void* const* d_in, const int* in_sizes, int n_in,
                              void* d_out, int out_size, void* d_ws, size_t ws_size,
                              hipStream_t stream) {
    const float* x = (const float*)d_in[0];
    float* out = (float*)d_out;

    float* xn   = (float*)d_ws;                             // NB*TN*CD  (6.29 MB)
    float* DAp  = xn + (size_t)NB * TN * CD;                // NB*TN*TN  (33.6 MB)
    float* DBp  = DAp + (size_t)NB * TN * TN;               // NB*TN*TN  (33.6 MB)
    ull*   rkg  = (ull*)(DBp + (size_t)NB * TN * TN);       // 2*NB*TN u64 (128 KB)
    int*   doneg = (int*)(rkg + 2 * (size_t)NB * TN);       // NB ints (pad 64)
    float* szg  = (float*)(doneg + 64);                     // NB*TN f32
    int*   gidg = (int*)(szg + (size_t)NB * TN);            // NB*TN i32
    ull*   mkg  = (ull*)(gidg + (size_t)NB * TN);           // NB*TN u64
    int*   metag = (int*)(mkg + (size_t)NB * TN);           // NB*4 ints

    float* dist_out   = out;
    float* labels_out = out + (size_t)NB * TN * TN;

    norm_kernel<<<NB * TN, 256, 0, stream>>>(x, xn);
    dim3 g2(16, 16, NB);
    dist_kernel<<<g2, 256, 0, stream>>>(xn, dist_out);

    const float* Dinit = dist_out;
    void* args[] = { (void*)&Dinit, (void*)&DAp, (void*)&DBp, (void*)&rkg,
                     (void*)&doneg, (void*)&szg, (void*)&gidg, (void*)&mkg,
                     (void*)&metag };
    hipLaunchCooperativeKernel((const void*)cluster_kernel, dim3(NWG), dim3(1024),
                               args, 0, stream);
    tail_kernel<<<NB, 1024, 0, stream>>>(DAp, DBp, szg, gidg, mkg, metag, labels_out);
}